// Round 1
// baseline (1006.196 us; speedup 1.0000x reference)
//
#include <hip/hip_runtime.h>
#include <hip/hip_bf16.h>
#include <stdint.h>
#include <stddef.h>

// Problem constants (GRUTridentDecoder: B=32,H=256,V=512,A=3,NANN=8,DEPTH=7)
#define NB 32
#define NH 256
#define NMID 512      // 2*H
#define NV 512
#define NA 3
#define NDEPTH 7
#define NNODES 3280   // (3^8-1)/2
#define NG 2304       // A*3H
#define MROWS (NNODES * NB)  // 104960

typedef __attribute__((ext_vector_type(8))) short bf16x8;
typedef __attribute__((ext_vector_type(4))) float f32x4;

__device__ __forceinline__ unsigned short f2bf(float x) {
    union { float f; unsigned u; } v; v.f = x;
    unsigned r = v.u + 0x7fffu + ((v.u >> 16) & 1u);
    return (unsigned short)(r >> 16);
}
__device__ __forceinline__ float sigm(float x) { return 1.0f / (1.0f + __expf(-x)); }
__device__ __forceinline__ float tanh_(float x) {
    x = fminf(fmaxf(x, -15.0f), 15.0f);
    float e = __expf(2.0f * x);
    return (e - 1.0f) / (e + 1.0f);
}

// ---- prep: cast weights fp32 -> bf16 (whh 2304x256, w1 512x256, w2 512x512)
__global__ void cast_weights(const float* __restrict__ whh, const float* __restrict__ w1,
                             const float* __restrict__ w2,
                             unsigned short* __restrict__ whh_b,
                             unsigned short* __restrict__ w1_b,
                             unsigned short* __restrict__ w2_b) {
    const int n_whh = NG * NH;          // 589824
    const int n_w1  = NMID * NH;        // 131072
    const int n_w2  = NV * NMID;        // 262144
    const int total = n_whh + n_w1 + n_w2;
    for (int i = blockIdx.x * blockDim.x + threadIdx.x; i < total;
         i += gridDim.x * blockDim.x) {
        if (i < n_whh) whh_b[i] = f2bf(whh[i]);
        else if (i < n_whh + n_w1) w1_b[i - n_whh] = f2bf(w1[i - n_whh]);
        else w2_b[i - n_whh - n_w1] = f2bf(w2[i - n_whh - n_w1]);
    }
}

// ---- prep: gx[b][col] = dot(ann_table[ann_ids[b]], w_ih[col]) + b_ih[col]
// one wave per output element; lanes split K=256 as 4 floats each
__global__ void gx_kernel(const float* __restrict__ ann_table, const int* __restrict__ ann_ids,
                          const float* __restrict__ w_ih, const float* __restrict__ b_ih,
                          float* __restrict__ gx) {
    int gw = blockIdx.x * (blockDim.x >> 6) + (threadIdx.x >> 6);
    int lane = threadIdx.x & 63;
    if (gw >= NB * NG) return;
    int b = gw / NG;
    int col = gw - b * NG;
    const float* xr = ann_table + (size_t)ann_ids[b] * NH;
    const float* wr = w_ih + (size_t)col * NH;
    float4 xv = *(const float4*)(xr + lane * 4);
    float4 wv = *(const float4*)(wr + lane * 4);
    float s = xv.x * wv.x + xv.y * wv.y + xv.z * wv.z + xv.w * wv.w;
    #pragma unroll
    for (int off = 32; off; off >>= 1) s += __shfl_down(s, off);
    if (lane == 0) gx[(size_t)b * NG + col] = s + b_ih[col];
}

// ---- prep: root hidden into node 0 (layout hid[(node*32+b)*256+h])
__global__ void init_root(const float* __restrict__ root, float* __restrict__ hid_f,
                          unsigned short* __restrict__ hid_b) {
    int i = blockIdx.x * blockDim.x + threadIdx.x;
    if (i < NB * NH) { float v = root[i]; hid_f[i] = v; hid_b[i] = f2bf(v); }
}

// ---- prep: preorder position of each level-order node
__global__ void posmap_kernel(int* __restrict__ posmap) {
    int n = blockIdx.x * blockDim.x + threadIdx.x;
    if (n >= NNODES) return;
    int start = 0, cnt = 1, l = 0;
    while (n >= start + cnt) { start += cnt; cnt *= 3; l++; }
    int p = n - start;
    int pw = 1;
    for (int j = 0; j < l - 1; j++) pw *= 3;   // 3^(l-1)
    int pos = 0;
    for (int k = 1; k <= l; k++) {
        int d = (p / pw) % 3;
        int e = NDEPTH - k + 1;                // subtree height exponent
        int p3 = 1; for (int j = 0; j < e; j++) p3 *= 3;
        pos += 1 + d * ((p3 - 1) / 2);
        pw /= 3;
    }
    posmap[n] = pos;
}

// ---- GRU level: rows = (parent_rel * 32 + b); computes gh GEMM + gates fused.
// grid: (parent_rows/16, 3 arity); block: 512 (8 waves). wave w owns h' in [w*32, w*32+32).
__global__ __launch_bounds__(512)
void gru_level(unsigned short* __restrict__ hid_b, float* __restrict__ hid_f,
               const unsigned short* __restrict__ whh_b,
               const float* __restrict__ b_hh, const float* __restrict__ gx,
               int start, int child_start) {
    int lane = threadIdx.x & 63;
    int wv = threadIdx.x >> 6;
    int a = blockIdx.y;
    int m0 = blockIdx.x * 16;
    int hp = wv * 32;
    int kg = (lane >> 4) * 8;
    int lr = lane & 15;

    const unsigned short* arow = hid_b + ((size_t)(start * NB + m0 + lr)) * NH + kg;
    const unsigned short* brow[3][2];
    #pragma unroll
    for (int t = 0; t < 3; ++t)
        #pragma unroll
        for (int ni = 0; ni < 2; ++ni)
            brow[t][ni] = whh_b + ((size_t)(a * 768 + t * 256 + hp + ni * 16 + lr)) * NH + kg;

    f32x4 acc[3][2] = {};
    for (int k0 = 0; k0 < NH; k0 += 32) {
        bf16x8 af = *(const bf16x8*)(arow + k0);
        #pragma unroll
        for (int t = 0; t < 3; ++t) {
            #pragma unroll
            for (int ni = 0; ni < 2; ++ni) {
                bf16x8 bf = *(const bf16x8*)(brow[t][ni] + k0);
                acc[t][ni] = __builtin_amdgcn_mfma_f32_16x16x32_bf16(af, bf, acc[t][ni], 0, 0, 0);
            }
        }
    }

    int rbase = (lane >> 4) * 4;
    #pragma unroll
    for (int ni = 0; ni < 2; ++ni) {
        int col = hp + ni * 16 + lr;
        #pragma unroll
        for (int j = 0; j < 4; ++j) {
            int row = m0 + rbase + j;
            int b = row & 31;
            int nrel = row >> 5;
            const float* gxb = gx + (size_t)b * NG + a * 768;
            float rpre = acc[0][ni][j] + b_hh[a * 768 + col] + gxb[col];
            float zpre = acc[1][ni][j] + b_hh[a * 768 + 256 + col] + gxb[256 + col];
            float hn   = acc[2][ni][j] + b_hh[a * 768 + 512 + col];
            float xn   = gxb[512 + col];
            float r = sigm(rpre), z = sigm(zpre);
            float nn = tanh_(xn + r * hn);
            float hpv = hid_f[((size_t)(start * NB + row)) * NH + col];
            float hnew = (1.0f - z) * nn + z * hpv;
            size_t crow = ((size_t)(child_start + nrel * 3 + a)) * NB + b;
            hid_f[crow * NH + col] = hnew;
            hid_b[crow * NH + col] = f2bf(hnew);
        }
    }
}

// ---- head1: mid = sigmoid(all_h @ w1^T + b1), M=104960 K=256 N=512
// block 256 (4 waves, 2x2), wave tile 32x32
__global__ __launch_bounds__(256)
void head1(const unsigned short* __restrict__ hid_b, const unsigned short* __restrict__ w1_b,
           const float* __restrict__ b1, unsigned short* __restrict__ mid_b) {
    int lane = threadIdx.x & 63;
    int wv = threadIdx.x >> 6;
    int wm = wv >> 1, wn = wv & 1;
    int m0 = blockIdx.x * 64 + wm * 32;
    int n0 = blockIdx.y * 64 + wn * 32;
    int kg = (lane >> 4) * 8, lr = lane & 15;
    const unsigned short* ar0 = hid_b + ((size_t)(m0 + lr)) * NH + kg;
    const unsigned short* ar1 = ar0 + 16 * NH;
    const unsigned short* br0 = w1_b + ((size_t)(n0 + lr)) * NH + kg;
    const unsigned short* br1 = br0 + 16 * NH;
    f32x4 acc[2][2] = {};
    for (int k0 = 0; k0 < NH; k0 += 32) {
        bf16x8 a0 = *(const bf16x8*)(ar0 + k0);
        bf16x8 a1 = *(const bf16x8*)(ar1 + k0);
        bf16x8 b0 = *(const bf16x8*)(br0 + k0);
        bf16x8 b1v = *(const bf16x8*)(br1 + k0);
        acc[0][0] = __builtin_amdgcn_mfma_f32_16x16x32_bf16(a0, b0, acc[0][0], 0, 0, 0);
        acc[0][1] = __builtin_amdgcn_mfma_f32_16x16x32_bf16(a0, b1v, acc[0][1], 0, 0, 0);
        acc[1][0] = __builtin_amdgcn_mfma_f32_16x16x32_bf16(a1, b0, acc[1][0], 0, 0, 0);
        acc[1][1] = __builtin_amdgcn_mfma_f32_16x16x32_bf16(a1, b1v, acc[1][1], 0, 0, 0);
    }
    int rbase = (lane >> 4) * 4;
    #pragma unroll
    for (int mi = 0; mi < 2; ++mi)
        #pragma unroll
        for (int ni = 0; ni < 2; ++ni) {
            int col = n0 + ni * 16 + lr;
            #pragma unroll
            for (int j = 0; j < 4; ++j) {
                int row = m0 + mi * 16 + rbase + j;
                float v = sigm(acc[mi][ni][j] + b1[col]);
                mid_b[(size_t)row * NMID + col] = f2bf(v);
            }
        }
}

// ---- head2: prod = mid @ w2^T + b2, permuted store out[pos][b][v]
__global__ __launch_bounds__(256)
void head2(const unsigned short* __restrict__ mid_b, const unsigned short* __restrict__ w2_b,
           const float* __restrict__ b2, const int* __restrict__ posmap,
           float* __restrict__ out) {
    int lane = threadIdx.x & 63;
    int wv = threadIdx.x >> 6;
    int wm = wv >> 1, wn = wv & 1;
    int m0 = blockIdx.x * 64 + wm * 32;
    int n0 = blockIdx.y * 64 + wn * 32;
    int kg = (lane >> 4) * 8, lr = lane & 15;
    const unsigned short* ar0 = mid_b + ((size_t)(m0 + lr)) * NMID + kg;
    const unsigned short* ar1 = ar0 + 16 * NMID;
    const unsigned short* br0 = w2_b + ((size_t)(n0 + lr)) * NMID + kg;
    const unsigned short* br1 = br0 + 16 * NMID;
    f32x4 acc[2][2] = {};
    for (int k0 = 0; k0 < NMID; k0 += 32) {
        bf16x8 a0 = *(const bf16x8*)(ar0 + k0);
        bf16x8 a1 = *(const bf16x8*)(ar1 + k0);
        bf16x8 b0 = *(const bf16x8*)(br0 + k0);
        bf16x8 b1v = *(const bf16x8*)(br1 + k0);
        acc[0][0] = __builtin_amdgcn_mfma_f32_16x16x32_bf16(a0, b0, acc[0][0], 0, 0, 0);
        acc[0][1] = __builtin_amdgcn_mfma_f32_16x16x32_bf16(a0, b1v, acc[0][1], 0, 0, 0);
        acc[1][0] = __builtin_amdgcn_mfma_f32_16x16x32_bf16(a1, b0, acc[1][0], 0, 0, 0);
        acc[1][1] = __builtin_amdgcn_mfma_f32_16x16x32_bf16(a1, b1v, acc[1][1], 0, 0, 0);
    }
    int rbase = (lane >> 4) * 4;
    #pragma unroll
    for (int mi = 0; mi < 2; ++mi)
        #pragma unroll
        for (int ni = 0; ni < 2; ++ni) {
            int col = n0 + ni * 16 + lr;
            #pragma unroll
            for (int j = 0; j < 4; ++j) {
                int row = m0 + mi * 16 + rbase + j;
                int b = row & 31;
                int node = row >> 5;
                int pos = posmap[node];
                out[((size_t)pos * NB + b) * NV + col] = acc[mi][ni][j] + b2[col];
            }
        }
}

extern "C" void kernel_launch(void* const* d_in, const int* in_sizes, int n_in,
                              void* d_out, int out_size, void* d_ws, size_t ws_size,
                              hipStream_t stream) {
    const float* root      = (const float*)d_in[0];
    const float* ann_table = (const float*)d_in[1];
    const float* w1        = (const float*)d_in[2];
    const float* b1        = (const float*)d_in[3];
    const float* w2        = (const float*)d_in[4];
    const float* b2        = (const float*)d_in[5];
    const float* w_ih      = (const float*)d_in[6];
    const float* w_hh      = (const float*)d_in[7];
    const float* b_ih      = (const float*)d_in[8];
    const float* b_hh      = (const float*)d_in[9];
    const int*   ann_ids   = (const int*)d_in[10];

    uint8_t* ws = (uint8_t*)d_ws;
    unsigned short* whh_b = (unsigned short*)ws; ws += (size_t)NG * NH * 2;      // 1.18 MB
    unsigned short* w1_b  = (unsigned short*)ws; ws += (size_t)NMID * NH * 2;    // 0.26 MB
    unsigned short* w2_b  = (unsigned short*)ws; ws += (size_t)NV * NMID * 2;    // 0.52 MB
    float* gx             = (float*)ws;          ws += (size_t)NB * NG * 4;      // 0.29 MB
    int* posmap           = (int*)ws;            ws += (size_t)NNODES * 4;       // 13 KB
    unsigned short* hid_b = (unsigned short*)ws; ws += (size_t)NNODES * NB * NH * 2; // 53.7 MB
    float* hid_f          = (float*)ws;          // 107.5 MB; mid aliases (dead after GRU)
    unsigned short* mid_b = (unsigned short*)hid_f;

    cast_weights<<<512, 256, 0, stream>>>(w_hh, w1, w2, whh_b, w1_b, w2_b);
    gx_kernel<<<(NB * NG) / 4, 256, 0, stream>>>(ann_table, ann_ids, w_ih, b_ih, gx);
    init_root<<<(NB * NH + 255) / 256, 256, 0, stream>>>(root, hid_f, hid_b);
    posmap_kernel<<<(NNODES + 255) / 256, 256, 0, stream>>>(posmap);

    int start = 0, cnt = 1;
    for (int l = 0; l < NDEPTH; ++l) {
        int child_start = start + cnt;
        dim3 grid(cnt * 2, 3);
        gru_level<<<grid, 512, 0, stream>>>(hid_b, hid_f, whh_b, b_hh, gx, start, child_start);
        start = child_start; cnt *= 3;
    }
    head1<<<dim3(MROWS / 64, NMID / 64), 256, 0, stream>>>(hid_b, w1_b, b1, mid_b);
    head2<<<dim3(MROWS / 64, NV / 64), 256, 0, stream>>>(mid_b, w2_b, b2, posmap, (float*)d_out);
}

// Round 2
// 655.770 us; speedup vs baseline: 1.5344x; 1.5344x over previous
//
#include <hip/hip_runtime.h>
#include <hip/hip_bf16.h>
#include <stdint.h>
#include <stddef.h>

// Problem constants (GRUTridentDecoder: B=32,H=256,V=512,A=3,NANN=8,DEPTH=7)
#define NB 32
#define NH 256
#define NMID 512      // 2*H
#define NV 512
#define NA 3
#define NDEPTH 7
#define NNODES 3280   // (3^8-1)/2
#define NG 2304       // A*3H
#define MROWS (NNODES * NB)  // 104960
#define HM 64         // fused-head rows per block

typedef __attribute__((ext_vector_type(8))) short bf16x8;
typedef __attribute__((ext_vector_type(4))) float f32x4;

__device__ __forceinline__ unsigned short f2bf(float x) {
    union { float f; unsigned u; } v; v.f = x;
    unsigned r = v.u + 0x7fffu + ((v.u >> 16) & 1u);
    return (unsigned short)(r >> 16);
}
__device__ __forceinline__ float sigm(float x) { return 1.0f / (1.0f + __expf(-x)); }
__device__ __forceinline__ float tanh_(float x) {
    x = fminf(fmaxf(x, -15.0f), 15.0f);
    float e = __expf(2.0f * x);
    return (e - 1.0f) / (e + 1.0f);
}

// ---- prep: cast weights fp32 -> bf16 (whh 2304x256, w1 512x256, w2 512x512)
__global__ void cast_weights(const float* __restrict__ whh, const float* __restrict__ w1,
                             const float* __restrict__ w2,
                             unsigned short* __restrict__ whh_b,
                             unsigned short* __restrict__ w1_b,
                             unsigned short* __restrict__ w2_b) {
    const int n_whh = NG * NH;          // 589824
    const int n_w1  = NMID * NH;        // 131072
    const int n_w2  = NV * NMID;        // 262144
    const int total = n_whh + n_w1 + n_w2;
    for (int i = blockIdx.x * blockDim.x + threadIdx.x; i < total;
         i += gridDim.x * blockDim.x) {
        if (i < n_whh) whh_b[i] = f2bf(whh[i]);
        else if (i < n_whh + n_w1) w1_b[i - n_whh] = f2bf(w1[i - n_whh]);
        else w2_b[i - n_whh - n_w1] = f2bf(w2[i - n_whh - n_w1]);
    }
}

// ---- prep: gx[b][col] = dot(ann_table[ann_ids[b]], w_ih[col]) + b_ih[col]
__global__ void gx_kernel(const float* __restrict__ ann_table, const int* __restrict__ ann_ids,
                          const float* __restrict__ w_ih, const float* __restrict__ b_ih,
                          float* __restrict__ gx) {
    int gw = blockIdx.x * (blockDim.x >> 6) + (threadIdx.x >> 6);
    int lane = threadIdx.x & 63;
    if (gw >= NB * NG) return;
    int b = gw / NG;
    int col = gw - b * NG;
    const float* xr = ann_table + (size_t)ann_ids[b] * NH;
    const float* wr = w_ih + (size_t)col * NH;
    float4 xv = *(const float4*)(xr + lane * 4);
    float4 wv = *(const float4*)(wr + lane * 4);
    float s = xv.x * wv.x + xv.y * wv.y + xv.z * wv.z + xv.w * wv.w;
    #pragma unroll
    for (int off = 32; off; off >>= 1) s += __shfl_down(s, off);
    if (lane == 0) gx[(size_t)b * NG + col] = s + b_ih[col];
}

// ---- prep: root hidden into node 0 (layout hid[(node*32+b)*256+h])
__global__ void init_root(const float* __restrict__ root, float* __restrict__ hid_f,
                          unsigned short* __restrict__ hid_b) {
    int i = blockIdx.x * blockDim.x + threadIdx.x;
    if (i < NB * NH) { float v = root[i]; hid_f[i] = v; hid_b[i] = f2bf(v); }
}

// ---- prep: preorder position of each level-order node
__global__ void posmap_kernel(int* __restrict__ posmap) {
    int n = blockIdx.x * blockDim.x + threadIdx.x;
    if (n >= NNODES) return;
    int start = 0, cnt = 1, l = 0;
    while (n >= start + cnt) { start += cnt; cnt *= 3; l++; }
    int p = n - start;
    int pw = 1;
    for (int j = 0; j < l - 1; j++) pw *= 3;   // 3^(l-1)
    int pos = 0;
    for (int k = 1; k <= l; k++) {
        int d = (p / pw) % 3;
        int e = NDEPTH - k + 1;                // subtree height exponent
        int p3 = 1; for (int j = 0; j < e; j++) p3 *= 3;
        pos += 1 + d * ((p3 - 1) / 2);
        pw /= 3;
    }
    posmap[n] = pos;
}

// ---- GRU level: rows = (parent_rel * 32 + b); computes gh GEMM + gates fused.
__global__ __launch_bounds__(512)
void gru_level(unsigned short* __restrict__ hid_b, float* __restrict__ hid_f,
               const unsigned short* __restrict__ whh_b,
               const float* __restrict__ b_hh, const float* __restrict__ gx,
               int start, int child_start) {
    int lane = threadIdx.x & 63;
    int wv = threadIdx.x >> 6;
    int a = blockIdx.y;
    int m0 = blockIdx.x * 16;
    int hp = wv * 32;
    int kg = (lane >> 4) * 8;
    int lr = lane & 15;

    const unsigned short* arow = hid_b + ((size_t)(start * NB + m0 + lr)) * NH + kg;
    const unsigned short* brow[3][2];
    #pragma unroll
    for (int t = 0; t < 3; ++t)
        #pragma unroll
        for (int ni = 0; ni < 2; ++ni)
            brow[t][ni] = whh_b + ((size_t)(a * 768 + t * 256 + hp + ni * 16 + lr)) * NH + kg;

    f32x4 acc[3][2] = {};
    for (int k0 = 0; k0 < NH; k0 += 32) {
        bf16x8 af = *(const bf16x8*)(arow + k0);
        #pragma unroll
        for (int t = 0; t < 3; ++t) {
            #pragma unroll
            for (int ni = 0; ni < 2; ++ni) {
                bf16x8 bfr = *(const bf16x8*)(brow[t][ni] + k0);
                acc[t][ni] = __builtin_amdgcn_mfma_f32_16x16x32_bf16(af, bfr, acc[t][ni], 0, 0, 0);
            }
        }
    }

    int rbase = (lane >> 4) * 4;
    #pragma unroll
    for (int ni = 0; ni < 2; ++ni) {
        int col = hp + ni * 16 + lr;
        #pragma unroll
        for (int j = 0; j < 4; ++j) {
            int row = m0 + rbase + j;
            int b = row & 31;
            int nrel = row >> 5;
            const float* gxb = gx + (size_t)b * NG + a * 768;
            float rpre = acc[0][ni][j] + b_hh[a * 768 + col] + gxb[col];
            float zpre = acc[1][ni][j] + b_hh[a * 768 + 256 + col] + gxb[256 + col];
            float hn   = acc[2][ni][j] + b_hh[a * 768 + 512 + col];
            float xn   = gxb[512 + col];
            float r = sigm(rpre), z = sigm(zpre);
            float nn = tanh_(xn + r * hn);
            float hpv = hid_f[((size_t)(start * NB + row)) * NH + col];
            float hnew = (1.0f - z) * nn + z * hpv;
            size_t crow = ((size_t)(child_start + nrel * 3 + a)) * NB + b;
            hid_f[crow * NH + col] = hnew;
            hid_b[crow * NH + col] = f2bf(hnew);
        }
    }
}

// ---- fused head: per block of 64 rows, mid = sigmoid(hid@w1^T+b1) in LDS (bf16,
// XOR-swizzled), then out = mid@w2^T + b2 with permuted store. 4 waves, each
// owns 128 output cols for the full 64-row tile.
__global__ __launch_bounds__(256, 2)
void head_fused(const unsigned short* __restrict__ hid_b,
                const unsigned short* __restrict__ w1_b, const float* __restrict__ b1,
                const unsigned short* __restrict__ w2_b, const float* __restrict__ b2,
                const int* __restrict__ posmap, float* __restrict__ out) {
    __shared__ unsigned short mid_s[HM * NMID];  // 64 KB

    int lane = threadIdx.x & 63;
    int wv = threadIdx.x >> 6;
    int mbase = blockIdx.x * HM;
    int lr = lane & 15;
    int kg = (lane >> 4) * 8;
    int rbase = (lane >> 4) * 4;
    int n0w = wv * 128;

    f32x4 acc[4][8];

    // ---- phase 1: mid tile
    #pragma unroll
    for (int mi = 0; mi < 4; ++mi)
        #pragma unroll
        for (int ni = 0; ni < 8; ++ni) acc[mi][ni] = (f32x4){0.f, 0.f, 0.f, 0.f};

    {
        const unsigned short* abase = hid_b + ((size_t)(mbase + lr)) * NH + kg;
        const unsigned short* bbase = w1_b + ((size_t)(n0w + lr)) * NH + kg;
        for (int k0 = 0; k0 < NH; k0 += 32) {
            bf16x8 af[4], bfr[8];
            #pragma unroll
            for (int mi = 0; mi < 4; ++mi) af[mi] = *(const bf16x8*)(abase + mi * 16 * NH + k0);
            #pragma unroll
            for (int ni = 0; ni < 8; ++ni) bfr[ni] = *(const bf16x8*)(bbase + ni * 16 * NH + k0);
            #pragma unroll
            for (int mi = 0; mi < 4; ++mi)
                #pragma unroll
                for (int ni = 0; ni < 8; ++ni)
                    acc[mi][ni] = __builtin_amdgcn_mfma_f32_16x16x32_bf16(af[mi], bfr[ni], acc[mi][ni], 0, 0, 0);
        }
    }
    // epilogue 1: sigmoid -> bf16 -> LDS (swizzled: byte ^= (row&7)<<4)
    #pragma unroll
    for (int mi = 0; mi < 4; ++mi)
        #pragma unroll
        for (int ni = 0; ni < 8; ++ni) {
            int col = n0w + ni * 16 + lr;
            float bv = b1[col];
            #pragma unroll
            for (int j = 0; j < 4; ++j) {
                int row = mi * 16 + rbase + j;
                float v = sigm(acc[mi][ni][j] + bv);
                int byteoff = (row * NMID + col) * 2;
                byteoff ^= (row & 7) << 4;
                *(unsigned short*)((char*)mid_s + byteoff) = f2bf(v);
            }
        }
    __syncthreads();

    // ---- phase 2: out tile
    #pragma unroll
    for (int mi = 0; mi < 4; ++mi)
        #pragma unroll
        for (int ni = 0; ni < 8; ++ni) acc[mi][ni] = (f32x4){0.f, 0.f, 0.f, 0.f};

    {
        const unsigned short* bbase = w2_b + ((size_t)(n0w + lr)) * NMID + kg;
        for (int k0 = 0; k0 < NMID; k0 += 32) {
            bf16x8 af[4], bfr[8];
            #pragma unroll
            for (int mi = 0; mi < 4; ++mi) {
                int row = mi * 16 + lr;
                int byteoff = (row * NMID + k0 + kg) * 2;
                byteoff ^= (row & 7) << 4;
                af[mi] = *(const bf16x8*)((char*)mid_s + byteoff);
            }
            #pragma unroll
            for (int ni = 0; ni < 8; ++ni) bfr[ni] = *(const bf16x8*)(bbase + ni * 16 * NMID + k0);
            #pragma unroll
            for (int mi = 0; mi < 4; ++mi)
                #pragma unroll
                for (int ni = 0; ni < 8; ++ni)
                    acc[mi][ni] = __builtin_amdgcn_mfma_f32_16x16x32_bf16(af[mi], bfr[ni], acc[mi][ni], 0, 0, 0);
        }
    }
    // epilogue 2: bias + permuted store
    #pragma unroll
    for (int mi = 0; mi < 4; ++mi)
        #pragma unroll
        for (int ni = 0; ni < 8; ++ni) {
            int col = n0w + ni * 16 + lr;
            float bv = b2[col];
            #pragma unroll
            for (int j = 0; j < 4; ++j) {
                int row = mbase + mi * 16 + rbase + j;
                int b = row & 31;
                int node = row >> 5;
                int pos = posmap[node];
                out[((size_t)pos * NB + b) * NV + col] = acc[mi][ni][j] + bv;
            }
        }
}

extern "C" void kernel_launch(void* const* d_in, const int* in_sizes, int n_in,
                              void* d_out, int out_size, void* d_ws, size_t ws_size,
                              hipStream_t stream) {
    const float* root      = (const float*)d_in[0];
    const float* ann_table = (const float*)d_in[1];
    const float* w1        = (const float*)d_in[2];
    const float* b1        = (const float*)d_in[3];
    const float* w2        = (const float*)d_in[4];
    const float* b2        = (const float*)d_in[5];
    const float* w_ih      = (const float*)d_in[6];
    const float* w_hh      = (const float*)d_in[7];
    const float* b_ih      = (const float*)d_in[8];
    const float* b_hh      = (const float*)d_in[9];
    const int*   ann_ids   = (const int*)d_in[10];

    uint8_t* ws = (uint8_t*)d_ws;
    unsigned short* whh_b = (unsigned short*)ws; ws += (size_t)NG * NH * 2;      // 1.18 MB
    unsigned short* w1_b  = (unsigned short*)ws; ws += (size_t)NMID * NH * 2;    // 0.26 MB
    unsigned short* w2_b  = (unsigned short*)ws; ws += (size_t)NV * NMID * 2;    // 0.52 MB
    float* gx             = (float*)ws;          ws += (size_t)NB * NG * 4;      // 0.29 MB
    int* posmap           = (int*)ws;            ws += (size_t)NNODES * 4;       // 13 KB
    unsigned short* hid_b = (unsigned short*)ws; ws += (size_t)NNODES * NB * NH * 2; // 53.7 MB
    float* hid_f          = (float*)ws;          // 107.5 MB

    cast_weights<<<512, 256, 0, stream>>>(w_hh, w1, w2, whh_b, w1_b, w2_b);
    gx_kernel<<<(NB * NG) / 4, 256, 0, stream>>>(ann_table, ann_ids, w_ih, b_ih, gx);
    init_root<<<(NB * NH + 255) / 256, 256, 0, stream>>>(root, hid_f, hid_b);
    posmap_kernel<<<(NNODES + 255) / 256, 256, 0, stream>>>(posmap);

    int start = 0, cnt = 1;
    for (int l = 0; l < NDEPTH; ++l) {
        int child_start = start + cnt;
        dim3 grid(cnt * 2, 3);
        gru_level<<<grid, 512, 0, stream>>>(hid_b, hid_f, whh_b, b_hh, gx, start, child_start);
        start = child_start; cnt *= 3;
    }
    head_fused<<<MROWS / HM, 256, 0, stream>>>(hid_b, w1_b, b1, w2_b, b2, posmap, (float*)d_out);
}